// Round 1
// baseline (462.656 us; speedup 1.0000x reference)
//
#include <hip/hip_runtime.h>

typedef unsigned short u16;
typedef unsigned int u32;
typedef __bf16 bf16_t;
typedef bf16_t bf16x8 __attribute__((ext_vector_type(8)));
typedef float f32x4 __attribute__((ext_vector_type(4)));

#define DM 768
#define HD 64
#define NH 12
#define NB 2
#define SEQ 4096
#define MR (NB * SEQ)  // 8192

__device__ __forceinline__ u16 f2bf(float f) {
  union { float f; u32 u; } v;
  v.f = f;
  u32 r = v.u + 0x7FFFu + ((v.u >> 16) & 1u);  // RNE, finite inputs only
  return (u16)(r >> 16);
}

__device__ __forceinline__ bf16x8 ldb8(const u16* p) {
  return *reinterpret_cast<const bf16x8*>(p);
}

__device__ __forceinline__ f32x4 mfma16(bf16x8 a, bf16x8 b, f32x4 c) {
  return __builtin_amdgcn_mfma_f32_16x16x32_bf16(a, b, c, 0, 0, 0);
}

#define GLDS16(g, l)                                              \
  __builtin_amdgcn_global_load_lds(                               \
      (const __attribute__((address_space(1))) void*)(g),         \
      (__attribute__((address_space(3))) void*)(l), 16, 0, 0)

// ---------------------------------------------------------------- converts
__global__ __launch_bounds__(256) void cvt_kernel(const float* __restrict__ src,
                                                  u16* __restrict__ dst, int n8) {
  int i = blockIdx.x * 256 + threadIdx.x;
  if (i >= n8) return;
  const float4* s = reinterpret_cast<const float4*>(src) + (size_t)i * 2;
  float4 a = s[0], b = s[1];
  union { u16 u[8]; uint4 v; } o;
  o.u[0] = f2bf(a.x); o.u[1] = f2bf(a.y); o.u[2] = f2bf(a.z); o.u[3] = f2bf(a.w);
  o.u[4] = f2bf(b.x); o.u[5] = f2bf(b.y); o.u[6] = f2bf(b.z); o.u[7] = f2bf(b.w);
  reinterpret_cast<uint4*>(dst)[i] = o.v;
}

__global__ __launch_bounds__(256) void cvt_w_kernel(const float* __restrict__ w0,
                                                    const float* __restrict__ w1,
                                                    const float* __restrict__ w2,
                                                    const float* __restrict__ w3,
                                                    u16* __restrict__ dst) {
  const float* src = (blockIdx.y == 0) ? w0 : (blockIdx.y == 1) ? w1
                   : (blockIdx.y == 2) ? w2 : w3;
  u16* d = dst + (size_t)blockIdx.y * DM * DM;
  int i = blockIdx.x * 256 + threadIdx.x;  // 0..73727
  const float4* s = reinterpret_cast<const float4*>(src) + (size_t)i * 2;
  float4 a = s[0], b = s[1];
  union { u16 u[8]; uint4 v; } o;
  o.u[0] = f2bf(a.x); o.u[1] = f2bf(a.y); o.u[2] = f2bf(a.z); o.u[3] = f2bf(a.w);
  o.u[4] = f2bf(b.x); o.u[5] = f2bf(b.y); o.u[6] = f2bf(b.z); o.u[7] = f2bf(b.w);
  reinterpret_cast<uint4*>(d)[i] = o.v;
}

// ---------------------------------------------------------------- QKV GEMM
// C[m,n] = sum_k A[m,k] * W[n,k] + bias[n]   (y = x @ W^T + b)
// 128x128 tile, BK=32, 4 waves (2x2), 16x16x32 MFMA. Output scattered to
// [B,H,S,64] bf16.
__global__ __launch_bounds__(256) void gemm_qkv_kernel(
    const u16* __restrict__ A, const u16* __restrict__ Wall,
    const float* __restrict__ b0, const float* __restrict__ b1,
    const float* __restrict__ b2, u16* __restrict__ O) {
  __shared__ __align__(16) u16 As[128 * 32];
  __shared__ __align__(16) u16 Bs[128 * 32];

  const int tid = threadIdx.x;
  const int w = tid >> 6, lane = tid & 63;
  const int l16 = lane & 15, lg = lane >> 4;
  const int wm = w >> 1, wn = w & 1;

  const int m0 = blockIdx.x * 128;
  const int n0 = blockIdx.y * 128;
  const int z = blockIdx.z;

  const u16* W = Wall + (size_t)z * DM * DM;
  const float* bias = (z == 0) ? b0 : ((z == 1) ? b1 : b2);
  u16* oz = O + (size_t)z * MR * DM;

  f32x4 acc[4][4];
#pragma unroll
  for (int i = 0; i < 4; ++i)
#pragma unroll
    for (int j = 0; j < 4; ++j) {
      acc[i][j][0] = 0.f; acc[i][j][1] = 0.f;
      acc[i][j][2] = 0.f; acc[i][j][3] = 0.f;
    }

  for (int k0 = 0; k0 < DM; k0 += 32) {
#pragma unroll
    for (int i = 0; i < 2; ++i) {
      const int c = (w * 2 + i) * 64 + lane;  // 16B chunk id, 0..511
      const int m = c >> 2, kc = c & 3;
      GLDS16(A + (size_t)(m0 + m) * DM + (k0 + kc * 8),
             As + (size_t)(w * 2 + i) * 512);
      GLDS16(W + (size_t)(n0 + m) * DM + (k0 + kc * 8),
             Bs + (size_t)(w * 2 + i) * 512);
    }
    __syncthreads();
    bf16x8 af[4], bfv[4];
#pragma unroll
    for (int i = 0; i < 4; ++i)
      af[i] = ldb8(As + (wm * 64 + i * 16 + l16) * 32 + lg * 8);
#pragma unroll
    for (int j = 0; j < 4; ++j)
      bfv[j] = ldb8(Bs + (wn * 64 + j * 16 + l16) * 32 + lg * 8);
#pragma unroll
    for (int i = 0; i < 4; ++i)
#pragma unroll
      for (int j = 0; j < 4; ++j)
        acc[i][j] = mfma16(af[i], bfv[j], acc[i][j]);
    __syncthreads();
  }

#pragma unroll
  for (int i = 0; i < 4; ++i) {
    const int gm = m0 + wm * 64 + i * 16 + lg * 4;
    const int bb = gm >> 12;          // /SEQ
    const int ss = gm & (SEQ - 1);
#pragma unroll
    for (int j = 0; j < 4; ++j) {
      const int gn = n0 + wn * 64 + j * 16 + l16;
      const int hh = gn >> 6, dd = gn & (HD - 1);
      const float bv = bias[gn];
      u16* op = oz + ((size_t)(bb * NH + hh) * SEQ + ss) * HD + dd;
#pragma unroll
      for (int r = 0; r < 4; ++r)
        op[(size_t)r * HD] = f2bf(acc[i][j][r] + bv);
    }
  }
}

// ---------------------------------------------------------------- out proj
__global__ __launch_bounds__(256) void gemm_out_kernel(
    const u16* __restrict__ A, const u16* __restrict__ W,
    const float* __restrict__ bias, float* __restrict__ Out) {
  __shared__ __align__(16) u16 As[128 * 32];
  __shared__ __align__(16) u16 Bs[128 * 32];

  const int tid = threadIdx.x;
  const int w = tid >> 6, lane = tid & 63;
  const int l16 = lane & 15, lg = lane >> 4;
  const int wm = w >> 1, wn = w & 1;

  const int m0 = blockIdx.x * 128;
  const int n0 = blockIdx.y * 128;

  f32x4 acc[4][4];
#pragma unroll
  for (int i = 0; i < 4; ++i)
#pragma unroll
    for (int j = 0; j < 4; ++j) {
      acc[i][j][0] = 0.f; acc[i][j][1] = 0.f;
      acc[i][j][2] = 0.f; acc[i][j][3] = 0.f;
    }

  for (int k0 = 0; k0 < DM; k0 += 32) {
#pragma unroll
    for (int i = 0; i < 2; ++i) {
      const int c = (w * 2 + i) * 64 + lane;
      const int m = c >> 2, kc = c & 3;
      GLDS16(A + (size_t)(m0 + m) * DM + (k0 + kc * 8),
             As + (size_t)(w * 2 + i) * 512);
      GLDS16(W + (size_t)(n0 + m) * DM + (k0 + kc * 8),
             Bs + (size_t)(w * 2 + i) * 512);
    }
    __syncthreads();
    bf16x8 af[4], bfv[4];
#pragma unroll
    for (int i = 0; i < 4; ++i)
      af[i] = ldb8(As + (wm * 64 + i * 16 + l16) * 32 + lg * 8);
#pragma unroll
    for (int j = 0; j < 4; ++j)
      bfv[j] = ldb8(Bs + (wn * 64 + j * 16 + l16) * 32 + lg * 8);
#pragma unroll
    for (int i = 0; i < 4; ++i)
#pragma unroll
      for (int j = 0; j < 4; ++j)
        acc[i][j] = mfma16(af[i], bfv[j], acc[i][j]);
    __syncthreads();
  }

#pragma unroll
  for (int i = 0; i < 4; ++i) {
    const int gm = m0 + wm * 64 + i * 16 + lg * 4;
#pragma unroll
    for (int j = 0; j < 4; ++j) {
      const int gn = n0 + wn * 64 + j * 16 + l16;
      const float bv = bias[gn];
      float* op = Out + (size_t)gm * DM + gn;
#pragma unroll
      for (int r = 0; r < 4; ++r)
        op[(size_t)r * DM] = acc[i][j][r] + bv;
    }
  }
}

// ---------------------------------------------------------------- attention
// grid (SEQ/64, NB*NH), 256 threads = 4 waves, 16 q-rows per wave, KV tile 64.
__global__ __launch_bounds__(256) void attn_kernel(
    const u16* __restrict__ Qg, const u16* __restrict__ Kg,
    const u16* __restrict__ Vg, u16* __restrict__ Og) {
  __shared__ __align__(16) u16 Kt[64][72];       // [kv][d], +8 pad
  __shared__ __align__(16) u16 Vt[64][72];       // [d][kv], +8 pad (V^T)
  __shared__ __align__(16) u16 Pt[4][16][72];    // per-wave P tile

  const int tid = threadIdx.x;
  const int w = tid >> 6, lane = tid & 63;
  const int l16 = lane & 15, lg = lane >> 4;

  const int qtile = blockIdx.x;
  const int bh = blockIdx.y;
  const int bb = bh / NH, hh = bh % NH;

  const size_t base = (size_t)bh * SEQ * HD;
  const u16* Qp = Qg + base;
  const u16* Kp = Kg + base;
  const u16* Vp = Vg + base;

  const int q0 = qtile * 64 + w * 16;

  bf16x8 qf[2];
  qf[0] = ldb8(Qp + (size_t)(q0 + l16) * HD + lg * 8);
  qf[1] = ldb8(Qp + (size_t)(q0 + l16) * HD + 32 + lg * 8);

  f32x4 oacc[4];
  float mrow[4], lrow[4];
#pragma unroll
  for (int i = 0; i < 4; ++i) {
    oacc[i][0] = 0.f; oacc[i][1] = 0.f; oacc[i][2] = 0.f; oacc[i][3] = 0.f;
    mrow[i] = -__builtin_inff();
    lrow[i] = 0.f;
  }

  const float SCL2E = 0.125f * 1.44269504088896340736f;  // 1/sqrt(64) * log2(e)

  const int nt = qtile + 1;
  for (int t = 0; t < nt; ++t) {
    __syncthreads();  // previous tile's LDS reads done
    {
      const int r = tid >> 2;            // 0..63
      const int c = (tid & 3) * 16;      // 0,16,32,48
      const u16* ks = Kp + (size_t)(t * 64 + r) * HD + c;
      *reinterpret_cast<uint4*>(&Kt[r][c]) = *reinterpret_cast<const uint4*>(ks);
      *reinterpret_cast<uint4*>(&Kt[r][c + 8]) =
          *reinterpret_cast<const uint4*>(ks + 8);
      const u16* vs = Vp + (size_t)(t * 64 + r) * HD + c;
      union { uint4 v[2]; u16 u[16]; } vv;
      vv.v[0] = *reinterpret_cast<const uint4*>(vs);
      vv.v[1] = *reinterpret_cast<const uint4*>(vs + 8);
#pragma unroll
      for (int j = 0; j < 16; ++j) Vt[c + j][r] = vv.u[j];  // transpose
    }
    __syncthreads();

    // ---- QK^T: S tile 16(q) x 64(kv), in log2-scaled units
    f32x4 st[4];
#pragma unroll
    for (int c = 0; c < 4; ++c) {
      bf16x8 kf0 = ldb8(&Kt[c * 16 + l16][lg * 8]);
      bf16x8 kf1 = ldb8(&Kt[c * 16 + l16][32 + lg * 8]);
      f32x4 sacc;
      sacc[0] = 0.f; sacc[1] = 0.f; sacc[2] = 0.f; sacc[3] = 0.f;
      sacc = mfma16(qf[0], kf0, sacc);
      sacc = mfma16(qf[1], kf1, sacc);
      st[c] = sacc;
    }

    const bool diag = (t == qtile);
#pragma unroll
    for (int c = 0; c < 4; ++c) {
#pragma unroll
      for (int i = 0; i < 4; ++i) {
        float v = st[c][i] * SCL2E;
        if (diag) {
          const int kvg = t * 64 + c * 16 + l16;
          const int qg = q0 + lg * 4 + i;
          if (kvg > qg) v = -__builtin_inff();
        }
        st[c][i] = v;
      }
    }

    // ---- online softmax per q-row (reg i), 16-lane group reduce
#pragma unroll
    for (int i = 0; i < 4; ++i) {
      float mx = fmaxf(fmaxf(st[0][i], st[1][i]), fmaxf(st[2][i], st[3][i]));
      mx = fmaxf(mx, __shfl_xor(mx, 1));
      mx = fmaxf(mx, __shfl_xor(mx, 2));
      mx = fmaxf(mx, __shfl_xor(mx, 4));
      mx = fmaxf(mx, __shfl_xor(mx, 8));
      const float mnew = fmaxf(mrow[i], mx);
      const float corr = exp2f(mrow[i] - mnew);
      mrow[i] = mnew;
      lrow[i] = lrow[i] * corr;
#pragma unroll
      for (int c2 = 0; c2 < 4; ++c2) oacc[c2][i] = oacc[c2][i] * corr;
      float rs = 0.f;
#pragma unroll
      for (int c = 0; c < 4; ++c) {
        const float p = exp2f(st[c][i] - mnew);
        st[c][i] = p;
        rs += p;
      }
      rs += __shfl_xor(rs, 1);
      rs += __shfl_xor(rs, 2);
      rs += __shfl_xor(rs, 4);
      rs += __shfl_xor(rs, 8);
      lrow[i] += rs;
    }

    // ---- P -> LDS (bf16), then PV
#pragma unroll
    for (int c = 0; c < 4; ++c)
#pragma unroll
      for (int i = 0; i < 4; ++i)
        Pt[w][lg * 4 + i][c * 16 + l16] = f2bf(st[c][i]);

#pragma unroll
    for (int h2 = 0; h2 < 2; ++h2) {
      bf16x8 pf = ldb8(&Pt[w][l16][h2 * 32 + lg * 8]);
#pragma unroll
      for (int c2 = 0; c2 < 4; ++c2) {
        bf16x8 vf = ldb8(&Vt[c2 * 16 + l16][h2 * 32 + lg * 8]);
        oacc[c2] = mfma16(pf, vf, oacc[c2]);
      }
    }
  }

  // ---- normalize + store preout [B,S,768] bf16
  u16* Op = Og + (size_t)bb * SEQ * DM + (size_t)hh * HD;
#pragma unroll
  for (int i = 0; i < 4; ++i) {
    const float inv = 1.f / lrow[i];
    const int ss = q0 + lg * 4 + i;
#pragma unroll
    for (int c2 = 0; c2 < 4; ++c2)
      Op[(size_t)ss * DM + c2 * 16 + l16] = f2bf(oacc[c2][i] * inv);
  }
}

// ---------------------------------------------------------------- launcher
extern "C" void kernel_launch(void* const* d_in, const int* in_sizes, int n_in,
                              void* d_out, int out_size, void* d_ws,
                              size_t ws_size, hipStream_t stream) {
  const float* x  = (const float*)d_in[0];
  const float* Wq = (const float*)d_in[1];
  const float* bq = (const float*)d_in[2];
  const float* Wk = (const float*)d_in[3];
  const float* bk = (const float*)d_in[4];
  const float* Wv = (const float*)d_in[5];
  const float* bv = (const float*)d_in[6];
  const float* Wo = (const float*)d_in[7];
  const float* bo = (const float*)d_in[8];
  float* out = (float*)d_out;

  u16* xb   = (u16*)d_ws;                       // [8192][768] bf16
  u16* Wall = xb + (size_t)MR * DM;             // 4 x [768][768] bf16 (q,k,v,o)
  u16* QKV  = Wall + (size_t)4 * DM * DM;       // 3 x [B,H,S,64] bf16
  u16* PRE  = QKV + (size_t)3 * MR * DM;        // [8192][768] bf16

  cvt_kernel<<<dim3(MR * DM / 8 / 256), 256, 0, stream>>>(x, xb, MR * DM / 8);
  cvt_w_kernel<<<dim3(DM * DM / 8 / 256, 4), 256, 0, stream>>>(Wq, Wk, Wv, Wo,
                                                               Wall);
  gemm_qkv_kernel<<<dim3(MR / 128, DM / 128, 3), 256, 0, stream>>>(
      xb, Wall, bq, bk, bv, QKV);
  attn_kernel<<<dim3(SEQ / 64, NB * NH), 256, 0, stream>>>(
      QKV, QKV + (size_t)MR * DM, QKV + (size_t)2 * MR * DM, PRE);
  gemm_out_kernel<<<dim3(MR / 128, DM / 128), 256, 0, stream>>>(
      PRE, Wall + (size_t)3 * DM * DM, bo, out);
}

// Round 3
// 311.334 us; speedup vs baseline: 1.4860x; 1.4860x over previous
//
#include <hip/hip_runtime.h>

typedef unsigned short u16;
typedef unsigned int u32;
typedef __bf16 bf16_t;
typedef bf16_t bf16x8 __attribute__((ext_vector_type(8)));
typedef float f32x4 __attribute__((ext_vector_type(4)));
typedef float f32x16 __attribute__((ext_vector_type(16)));

#define DM 768
#define HD 64
#define NH 12
#define NB 2
#define SEQ 4096
#define MR (NB * SEQ)  // 8192

#define SCL2E_F (0.125f * 1.44269504088896340736f)  // 1/sqrt(64) * log2(e)

__device__ __forceinline__ u16 f2bf(float f) {
  union { float f; u32 u; } v;
  v.f = f;
  u32 r = v.u + 0x7FFFu + ((v.u >> 16) & 1u);  // RNE, finite inputs only
  return (u16)(r >> 16);
}

__device__ __forceinline__ u32 pack2(float a, float b) {
  return (u32)f2bf(a) | ((u32)f2bf(b) << 16);
}

__device__ __forceinline__ bf16x8 ldb8(const u16* p) {
  return *reinterpret_cast<const bf16x8*>(p);
}

__device__ __forceinline__ f32x4 mfma16(bf16x8 a, bf16x8 b, f32x4 c) {
  return __builtin_amdgcn_mfma_f32_16x16x32_bf16(a, b, c, 0, 0, 0);
}

__device__ __forceinline__ f32x16 mfma32(bf16x8 a, bf16x8 b, f32x16 c) {
  return __builtin_amdgcn_mfma_f32_32x32x16_bf16(a, b, c, 0, 0, 0);
}

#define GLDS16(g, l)                                              \
  __builtin_amdgcn_global_load_lds(                               \
      (const __attribute__((address_space(1))) void*)(g),         \
      (__attribute__((address_space(3))) void*)(l), 16, 0, 0)

// ---------------------------------------------------------------- converts
__global__ __launch_bounds__(256) void cvt_kernel(const float* __restrict__ src,
                                                  u16* __restrict__ dst, int n8) {
  int i = blockIdx.x * 256 + threadIdx.x;
  if (i >= n8) return;
  const float4* s = reinterpret_cast<const float4*>(src) + (size_t)i * 2;
  float4 a = s[0], b = s[1];
  union { u16 u[8]; uint4 v; } o;
  o.u[0] = f2bf(a.x); o.u[1] = f2bf(a.y); o.u[2] = f2bf(a.z); o.u[3] = f2bf(a.w);
  o.u[4] = f2bf(b.x); o.u[5] = f2bf(b.y); o.u[6] = f2bf(b.z); o.u[7] = f2bf(b.w);
  reinterpret_cast<uint4*>(dst)[i] = o.v;
}

__global__ __launch_bounds__(256) void cvt_w_kernel(const float* __restrict__ w0,
                                                    const float* __restrict__ w1,
                                                    const float* __restrict__ w2,
                                                    const float* __restrict__ w3,
                                                    u16* __restrict__ dst) {
  const float* src = (blockIdx.y == 0) ? w0 : (blockIdx.y == 1) ? w1
                   : (blockIdx.y == 2) ? w2 : w3;
  u16* d = dst + (size_t)blockIdx.y * DM * DM;
  int i = blockIdx.x * 256 + threadIdx.x;
  const float4* s = reinterpret_cast<const float4*>(src) + (size_t)i * 2;
  float4 a = s[0], b = s[1];
  union { u16 u[8]; uint4 v; } o;
  o.u[0] = f2bf(a.x); o.u[1] = f2bf(a.y); o.u[2] = f2bf(a.z); o.u[3] = f2bf(a.w);
  o.u[4] = f2bf(b.x); o.u[5] = f2bf(b.y); o.u[6] = f2bf(b.z); o.u[7] = f2bf(b.w);
  reinterpret_cast<uint4*>(d)[i] = o.v;
}

// ---------------------------------------------------------------- QKV GEMM
// C[m,n] = sum_k A[m,k] * W[n,k] + bias[n]
// z==0 (Q): scaled by SCL2E, layout [bh][s][64]
// z==1 (K): layout [bh][s][64]
// z==2 (V): TRANSPOSED layout [bh][d][s]  (V^T, packed uint2 stores)
__global__ __launch_bounds__(256) void gemm_qkv_kernel(
    const u16* __restrict__ A, const u16* __restrict__ Wall,
    const float* __restrict__ b0, const float* __restrict__ b1,
    const float* __restrict__ b2, u16* __restrict__ O) {
  __shared__ __align__(16) u16 As[128 * 32];
  __shared__ __align__(16) u16 Bs[128 * 32];

  const int tid = threadIdx.x;
  const int w = tid >> 6, lane = tid & 63;
  const int l16 = lane & 15, lg = lane >> 4;
  const int wm = w >> 1, wn = w & 1;

  const int m0 = blockIdx.x * 128;
  const int n0 = blockIdx.y * 128;
  const int z = blockIdx.z;

  const u16* W = Wall + (size_t)z * DM * DM;
  const float* bias = (z == 0) ? b0 : ((z == 1) ? b1 : b2);
  u16* oz = O + (size_t)z * MR * DM;
  const float qscale = (z == 0) ? SCL2E_F : 1.f;

  f32x4 acc[4][4];
#pragma unroll
  for (int i = 0; i < 4; ++i)
#pragma unroll
    for (int j = 0; j < 4; ++j) {
      acc[i][j][0] = 0.f; acc[i][j][1] = 0.f;
      acc[i][j][2] = 0.f; acc[i][j][3] = 0.f;
    }

  for (int k0 = 0; k0 < DM; k0 += 32) {
#pragma unroll
    for (int i = 0; i < 2; ++i) {
      const int c = (w * 2 + i) * 64 + lane;
      const int m = c >> 2, kc = c & 3;
      GLDS16(A + (size_t)(m0 + m) * DM + (k0 + kc * 8),
             As + (size_t)(w * 2 + i) * 512);
      GLDS16(W + (size_t)(n0 + m) * DM + (k0 + kc * 8),
             Bs + (size_t)(w * 2 + i) * 512);
    }
    __syncthreads();
    bf16x8 af[4], bfv[4];
#pragma unroll
    for (int i = 0; i < 4; ++i)
      af[i] = ldb8(As + (wm * 64 + i * 16 + l16) * 32 + lg * 8);
#pragma unroll
    for (int j = 0; j < 4; ++j)
      bfv[j] = ldb8(Bs + (wn * 64 + j * 16 + l16) * 32 + lg * 8);
#pragma unroll
    for (int i = 0; i < 4; ++i)
#pragma unroll
      for (int j = 0; j < 4; ++j)
        acc[i][j] = mfma16(af[i], bfv[j], acc[i][j]);
    __syncthreads();
  }

#pragma unroll
  for (int i = 0; i < 4; ++i) {
    const int gm = m0 + wm * 64 + i * 16 + lg * 4;
    const int bb = gm >> 12;          // /SEQ
    const int ss = gm & (SEQ - 1);
#pragma unroll
    for (int j = 0; j < 4; ++j) {
      const int gn = n0 + wn * 64 + j * 16 + l16;
      const int hh = gn >> 6, dd = gn & (HD - 1);
      const float bv = bias[gn];
      if (z == 2) {
        union { u16 u[4]; uint2 v; } pk;
#pragma unroll
        for (int r = 0; r < 4; ++r) pk.u[r] = f2bf(acc[i][j][r] + bv);
        *reinterpret_cast<uint2*>(
            oz + ((size_t)(bb * NH + hh) * HD + dd) * SEQ + ss) = pk.v;
      } else {
        u16* op = oz + ((size_t)(bb * NH + hh) * SEQ + ss) * HD + dd;
#pragma unroll
        for (int r = 0; r < 4; ++r)
          op[(size_t)r * HD] = f2bf((acc[i][j][r] + bv) * qscale);
      }
    }
  }
}

// ---------------------------------------------------------------- out proj
__global__ __launch_bounds__(256) void gemm_out_kernel(
    const u16* __restrict__ A, const u16* __restrict__ W,
    const float* __restrict__ bias, float* __restrict__ Out) {
  __shared__ __align__(16) u16 As[128 * 32];
  __shared__ __align__(16) u16 Bs[128 * 32];

  const int tid = threadIdx.x;
  const int w = tid >> 6, lane = tid & 63;
  const int l16 = lane & 15, lg = lane >> 4;
  const int wm = w >> 1, wn = w & 1;

  const int m0 = blockIdx.x * 128;
  const int n0 = blockIdx.y * 128;

  f32x4 acc[4][4];
#pragma unroll
  for (int i = 0; i < 4; ++i)
#pragma unroll
    for (int j = 0; j < 4; ++j) {
      acc[i][j][0] = 0.f; acc[i][j][1] = 0.f;
      acc[i][j][2] = 0.f; acc[i][j][3] = 0.f;
    }

  for (int k0 = 0; k0 < DM; k0 += 32) {
#pragma unroll
    for (int i = 0; i < 2; ++i) {
      const int c = (w * 2 + i) * 64 + lane;
      const int m = c >> 2, kc = c & 3;
      GLDS16(A + (size_t)(m0 + m) * DM + (k0 + kc * 8),
             As + (size_t)(w * 2 + i) * 512);
      GLDS16(W + (size_t)(n0 + m) * DM + (k0 + kc * 8),
             Bs + (size_t)(w * 2 + i) * 512);
    }
    __syncthreads();
    bf16x8 af[4], bfv[4];
#pragma unroll
    for (int i = 0; i < 4; ++i)
      af[i] = ldb8(As + (wm * 64 + i * 16 + l16) * 32 + lg * 8);
#pragma unroll
    for (int j = 0; j < 4; ++j)
      bfv[j] = ldb8(Bs + (wn * 64 + j * 16 + l16) * 32 + lg * 8);
#pragma unroll
    for (int i = 0; i < 4; ++i)
#pragma unroll
      for (int j = 0; j < 4; ++j)
        acc[i][j] = mfma16(af[i], bfv[j], acc[i][j]);
    __syncthreads();
  }

#pragma unroll
  for (int i = 0; i < 4; ++i) {
    const int gm = m0 + wm * 64 + i * 16 + lg * 4;
#pragma unroll
    for (int j = 0; j < 4; ++j) {
      const int gn = n0 + wn * 64 + j * 16 + l16;
      const float bv = bias[gn];
      float* op = Out + (size_t)gm * DM + gn;
#pragma unroll
      for (int r = 0; r < 4; ++r)
        op[(size_t)r * DM] = acc[i][j][r] + bv;
    }
  }
}

// ---------------------------------------------------------------- attention
// grid (32, 24): 128 q-rows per block, 4 waves x 32 q-rows, KV tile 64.
// Swapped QK^T (32x32x16): lane holds S^T[kv=crow(reg,hi)][q=lane&31].
// PV: O^T = mfma(A=V^T frag from LDS, B=P frag built via shfl_xor(32)).
__global__ __launch_bounds__(256) void attn_kernel(
    const u16* __restrict__ Qg, const u16* __restrict__ Kg,
    const u16* __restrict__ VTg, u16* __restrict__ Og) {
  __shared__ __align__(16) u16 Kt[64][72];   // [kv][d], +8 pad
  __shared__ __align__(16) u16 Vt[64][72];   // [d][kv], +8 pad (V^T)

  const int tid = threadIdx.x;
  const int w = tid >> 6, lane = tid & 63;
  const int l32 = lane & 31, hi = lane >> 5;

  const int qt = blockIdx.x;   // 0..31
  const int bh = blockIdx.y;   // 0..23
  const int bb = bh / NH, hh = bh % NH;

  const u16* Qp = Qg + (size_t)bh * SEQ * HD;
  const u16* Kp = Kg + (size_t)bh * SEQ * HD;
  const u16* VTp = VTg + (size_t)bh * HD * SEQ;

  const int qw0 = qt * 128 + w * 32;
  const int qlane = qw0 + l32;

  // Q fragments (B-operand): qf[c][j] = Q[q][c*16 + hi*8 + j]  (pre-scaled)
  bf16x8 qf[4];
#pragma unroll
  for (int c = 0; c < 4; ++c)
    qf[c] = ldb8(Qp + (size_t)qlane * HD + c * 16 + hi * 8);

  f32x16 oacc[2];  // O^T[32*db + crow(reg,hi)][q=l32]
#pragma unroll
  for (int db = 0; db < 2; ++db)
#pragma unroll
    for (int r = 0; r < 16; ++r) oacc[db][r] = 0.f;
  float mrun = -__builtin_inff();
  float lsum = 0.f;

  // staging coords: 8 threads per 64-elem row, rows srow and srow+32
  const int srow = tid >> 3;        // 0..31
  const int sc8 = (tid & 7) * 8;

  const int NT = 2 * qt + 2;
  for (int t = 0; t < NT; ++t) {
    const int kv0 = t * 64;
    // issue stage loads early (hide under prev-tile compute tail + barrier)
    uint4 sK0 = *reinterpret_cast<const uint4*>(
        Kp + (size_t)(kv0 + srow) * HD + sc8);
    uint4 sK1 = *reinterpret_cast<const uint4*>(
        Kp + (size_t)(kv0 + srow + 32) * HD + sc8);
    uint4 sV0 = *reinterpret_cast<const uint4*>(
        VTp + (size_t)srow * SEQ + kv0 + sc8);
    uint4 sV1 = *reinterpret_cast<const uint4*>(
        VTp + (size_t)(srow + 32) * SEQ + kv0 + sc8);
    __syncthreads();  // all waves done reading previous tile
    *reinterpret_cast<uint4*>(&Kt[srow][sc8]) = sK0;
    *reinterpret_cast<uint4*>(&Kt[srow + 32][sc8]) = sK1;
    *reinterpret_cast<uint4*>(&Vt[srow][sc8]) = sV0;
    *reinterpret_cast<uint4*>(&Vt[srow + 32][sc8]) = sV1;
    __syncthreads();

    if (kv0 <= qw0 + 31) {  // wave has unmasked work in this tile
      // ---- QK^T (swapped): st[b] = S^T[kv=32b+crow][q]
      f32x16 st[2];
#pragma unroll
      for (int b = 0; b < 2; ++b) {
#pragma unroll
        for (int r = 0; r < 16; ++r) st[b][r] = 0.f;
#pragma unroll
        for (int c = 0; c < 4; ++c) {
          bf16x8 kf = ldb8(&Kt[b * 32 + l32][c * 16 + hi * 8]);
          st[b] = mfma32(kf, qf[c], st[b]);
        }
      }

      // ---- causal mask (only when tile straddles diagonal for this wave)
      if (kv0 + 63 > qw0) {
#pragma unroll
        for (int b = 0; b < 2; ++b)
#pragma unroll
          for (int r = 0; r < 16; ++r) {
            const int kvi = kv0 + b * 32 + (r & 3) + 8 * (r >> 2) + 4 * hi;
            if (kvi > qlane) st[b][r] = -__builtin_inff();
          }
      }

      // ---- row max: in-lane tree + partner combine (shfl_xor 32)
      float mt = st[0][0];
#pragma unroll
      for (int r = 1; r < 16; ++r) mt = fmaxf(mt, st[0][r]);
#pragma unroll
      for (int r = 0; r < 16; ++r) mt = fmaxf(mt, st[1][r]);
      mt = fmaxf(mt, __shfl_xor(mt, 32));
      const float mnew = fmaxf(mrun, mt);
      const float corr = exp2f(mrun - mnew);  // 0 on first tile
      mrun = mnew;

      // ---- exp (values already in log2 units) + partial row sum
      float rs0 = 0.f, rs1 = 0.f;
#pragma unroll
      for (int r = 0; r < 16; ++r) {
        float p = exp2f(st[0][r] - mnew);
        st[0][r] = p; rs0 += p;
      }
#pragma unroll
      for (int r = 0; r < 16; ++r) {
        float p = exp2f(st[1][r] - mnew);
        st[1][r] = p; rs1 += p;
      }
      lsum = lsum * corr + rs0 + rs1;

      // ---- rescale O^T
#pragma unroll
      for (int db = 0; db < 2; ++db)
#pragma unroll
        for (int r = 0; r < 16; ++r) oacc[db][r] *= corr;

      // ---- pack P to bf16 fragments (shfl partner exchange) and PV
#pragma unroll
      for (int b = 0; b < 2; ++b) {
#pragma unroll
        for (int h = 0; h < 2; ++h) {  // kv 16-chunk c = 2b + h
          u32 a0 = pack2(st[b][h * 8 + 0], st[b][h * 8 + 1]);
          u32 a1 = pack2(st[b][h * 8 + 2], st[b][h * 8 + 3]);
          u32 a2 = pack2(st[b][h * 8 + 4], st[b][h * 8 + 5]);
          u32 a3 = pack2(st[b][h * 8 + 6], st[b][h * 8 + 7]);
          const u32 p0 = (u32)__shfl_xor((int)a0, 32);
          const u32 p1 = (u32)__shfl_xor((int)a1, 32);
          const u32 p2 = (u32)__shfl_xor((int)a2, 32);
          const u32 p3 = (u32)__shfl_xor((int)a3, 32);
          union { u32 w[4]; bf16x8 v; } pb;
          pb.w[0] = hi ? p2 : a0;
          pb.w[1] = hi ? p3 : a1;
          pb.w[2] = hi ? a2 : p0;
          pb.w[3] = hi ? a3 : p1;
          const int c = 2 * b + h;
#pragma unroll
          for (int db = 0; db < 2; ++db) {
            bf16x8 vf = ldb8(&Vt[db * 32 + l32][c * 16 + hi * 8]);
            oacc[db] = mfma32(vf, pb.v, oacc[db]);
          }
        }
      }
    }
  }

  // ---- combine partner halves of l, normalize, store O[q][d] bf16
  const float ltot = lsum + __shfl_xor(lsum, 32);
  const float linv = 1.f / ltot;

  u16* Op = Og + ((size_t)bb * SEQ + qlane) * DM + hh * HD;
#pragma unroll
  for (int db = 0; db < 2; ++db)
#pragma unroll
    for (int r = 0; r < 16; r += 2) {
      const int d = db * 32 + (r & 3) + 8 * (r >> 2) + 4 * hi;
      u32 pk = pack2(oacc[db][r] * linv, oacc[db][r + 1] * linv);
      *reinterpret_cast<u32*>(Op + d) = pk;
    }
}

// ---------------------------------------------------------------- launcher
extern "C" void kernel_launch(void* const* d_in, const int* in_sizes, int n_in,
                              void* d_out, int out_size, void* d_ws,
                              size_t ws_size, hipStream_t stream) {
  const float* x  = (const float*)d_in[0];
  const float* Wq = (const float*)d_in[1];
  const float* bq = (const float*)d_in[2];
  const float* Wk = (const float*)d_in[3];
  const float* bk = (const float*)d_in[4];
  const float* Wv = (const float*)d_in[5];
  const float* bv = (const float*)d_in[6];
  const float* Wo = (const float*)d_in[7];
  const float* bo = (const float*)d_in[8];
  float* out = (float*)d_out;

  u16* xb   = (u16*)d_ws;                       // [8192][768] bf16
  u16* Wall = xb + (size_t)MR * DM;             // 4 x [768][768] bf16
  u16* QKV  = Wall + (size_t)4 * DM * DM;       // Q,K: [bh][s][64]; V: [bh][d][s]
  u16* PRE  = QKV + (size_t)3 * MR * DM;        // [8192][768] bf16

  cvt_kernel<<<dim3(MR * DM / 8 / 256), 256, 0, stream>>>(x, xb, MR * DM / 8);
  cvt_w_kernel<<<dim3(DM * DM / 8 / 256, 4), 256, 0, stream>>>(Wq, Wk, Wv, Wo,
                                                               Wall);
  gemm_qkv_kernel<<<dim3(MR / 128, DM / 128, 3), 256, 0, stream>>>(
      xb, Wall, bq, bk, bv, QKV);
  attn_kernel<<<dim3(SEQ / 128, NB * NH), 256, 0, stream>>>(
      QKV, QKV + (size_t)MR * DM, QKV + (size_t)2 * MR * DM, PRE);
  gemm_out_kernel<<<dim3(MR / 128, DM / 128), 256, 0, stream>>>(
      PRE, Wall + (size_t)3 * DM * DM, bo, out);
}

// Round 4
// 213.308 us; speedup vs baseline: 2.1690x; 1.4595x over previous
//
#include <hip/hip_runtime.h>

typedef unsigned short u16;
typedef unsigned int u32;
typedef __bf16 bf16_t;
typedef bf16_t bf16x8 __attribute__((ext_vector_type(8)));
typedef float f32x4 __attribute__((ext_vector_type(4)));
typedef float f32x16 __attribute__((ext_vector_type(16)));

#define DM 768
#define HD 64
#define NH 12
#define NB 2
#define SEQ 4096
#define MR (NB * SEQ)  // 8192

#define SCL2E_F (0.125f * 1.44269504088896340736f)  // 1/sqrt(64) * log2(e)

__device__ __forceinline__ u16 f2bf(float f) {
  union { float f; u32 u; } v;
  v.f = f;
  u32 r = v.u + 0x7FFFu + ((v.u >> 16) & 1u);  // RNE, finite inputs only
  return (u16)(r >> 16);
}

// hardware pack: lo16 = bf16(a), hi16 = bf16(b)
__device__ __forceinline__ u32 cvtpk(float a, float b) {
  u32 r;
  asm("v_cvt_pk_bf16_f32 %0, %1, %2" : "=v"(r) : "v"(a), "v"(b));
  return r;
}

__device__ __forceinline__ bf16x8 ldb8(const u16* p) {
  return *reinterpret_cast<const bf16x8*>(p);
}

__device__ __forceinline__ f32x4 mfma16(bf16x8 a, bf16x8 b, f32x4 c) {
  return __builtin_amdgcn_mfma_f32_16x16x32_bf16(a, b, c, 0, 0, 0);
}

__device__ __forceinline__ f32x16 mfma32(bf16x8 a, bf16x8 b, f32x16 c) {
  return __builtin_amdgcn_mfma_f32_32x32x16_bf16(a, b, c, 0, 0, 0);
}

#define GLDS16(g, l)                                              \
  __builtin_amdgcn_global_load_lds(                               \
      (const __attribute__((address_space(1))) void*)(g),         \
      (__attribute__((address_space(3))) void*)(l), 16, 0, 0)

// ---------------------------------------------------------------- converts
__global__ __launch_bounds__(256) void cvt_kernel(const float* __restrict__ src,
                                                  u16* __restrict__ dst, int n8) {
  int i = blockIdx.x * 256 + threadIdx.x;
  if (i >= n8) return;
  const float4* s = reinterpret_cast<const float4*>(src) + (size_t)i * 2;
  float4 a = s[0], b = s[1];
  union { u16 u[8]; uint4 v; } o;
  o.u[0] = f2bf(a.x); o.u[1] = f2bf(a.y); o.u[2] = f2bf(a.z); o.u[3] = f2bf(a.w);
  o.u[4] = f2bf(b.x); o.u[5] = f2bf(b.y); o.u[6] = f2bf(b.z); o.u[7] = f2bf(b.w);
  reinterpret_cast<uint4*>(dst)[i] = o.v;
}

__global__ __launch_bounds__(256) void cvt_w_kernel(const float* __restrict__ w0,
                                                    const float* __restrict__ w1,
                                                    const float* __restrict__ w2,
                                                    const float* __restrict__ w3,
                                                    u16* __restrict__ dst) {
  const float* src = (blockIdx.y == 0) ? w0 : (blockIdx.y == 1) ? w1
                   : (blockIdx.y == 2) ? w2 : w3;
  u16* d = dst + (size_t)blockIdx.y * DM * DM;
  int i = blockIdx.x * 256 + threadIdx.x;
  const float4* s = reinterpret_cast<const float4*>(src) + (size_t)i * 2;
  float4 a = s[0], b = s[1];
  union { u16 u[8]; uint4 v; } o;
  o.u[0] = f2bf(a.x); o.u[1] = f2bf(a.y); o.u[2] = f2bf(a.z); o.u[3] = f2bf(a.w);
  o.u[4] = f2bf(b.x); o.u[5] = f2bf(b.y); o.u[6] = f2bf(b.z); o.u[7] = f2bf(b.w);
  reinterpret_cast<uint4*>(d)[i] = o.v;
}

// ---------------------------------------------------------------- QKV GEMM
// C[m,n] = sum_k A[m,k] * W[n,k] + bias[n]
// z==0 (Q): scaled by SCL2E, layout [bh][s][64]
// z==1 (K): layout [bh][s][64]
// z==2 (V): TRANSPOSED layout [bh][d][s]  (V^T, packed uint2 stores)
__global__ __launch_bounds__(256) void gemm_qkv_kernel(
    const u16* __restrict__ A, const u16* __restrict__ Wall,
    const float* __restrict__ b0, const float* __restrict__ b1,
    const float* __restrict__ b2, u16* __restrict__ O) {
  __shared__ __align__(16) u16 As[128 * 32];
  __shared__ __align__(16) u16 Bs[128 * 32];

  const int tid = threadIdx.x;
  const int w = tid >> 6, lane = tid & 63;
  const int l16 = lane & 15, lg = lane >> 4;
  const int wm = w >> 1, wn = w & 1;

  const int m0 = blockIdx.x * 128;
  const int n0 = blockIdx.y * 128;
  const int z = blockIdx.z;

  const u16* W = Wall + (size_t)z * DM * DM;
  const float* bias = (z == 0) ? b0 : ((z == 1) ? b1 : b2);
  u16* oz = O + (size_t)z * MR * DM;
  const float qscale = (z == 0) ? SCL2E_F : 1.f;

  f32x4 acc[4][4];
#pragma unroll
  for (int i = 0; i < 4; ++i)
#pragma unroll
    for (int j = 0; j < 4; ++j) {
      acc[i][j][0] = 0.f; acc[i][j][1] = 0.f;
      acc[i][j][2] = 0.f; acc[i][j][3] = 0.f;
    }

  for (int k0 = 0; k0 < DM; k0 += 32) {
#pragma unroll
    for (int i = 0; i < 2; ++i) {
      const int c = (w * 2 + i) * 64 + lane;
      const int m = c >> 2, kc = c & 3;
      GLDS16(A + (size_t)(m0 + m) * DM + (k0 + kc * 8),
             As + (size_t)(w * 2 + i) * 512);
      GLDS16(W + (size_t)(n0 + m) * DM + (k0 + kc * 8),
             Bs + (size_t)(w * 2 + i) * 512);
    }
    __syncthreads();
    bf16x8 af[4], bfv[4];
#pragma unroll
    for (int i = 0; i < 4; ++i)
      af[i] = ldb8(As + (wm * 64 + i * 16 + l16) * 32 + lg * 8);
#pragma unroll
    for (int j = 0; j < 4; ++j)
      bfv[j] = ldb8(Bs + (wn * 64 + j * 16 + l16) * 32 + lg * 8);
#pragma unroll
    for (int i = 0; i < 4; ++i)
#pragma unroll
      for (int j = 0; j < 4; ++j)
        acc[i][j] = mfma16(af[i], bfv[j], acc[i][j]);
    __syncthreads();
  }

#pragma unroll
  for (int i = 0; i < 4; ++i) {
    const int gm = m0 + wm * 64 + i * 16 + lg * 4;
    const int bb = gm >> 12;          // /SEQ
    const int ss = gm & (SEQ - 1);
#pragma unroll
    for (int j = 0; j < 4; ++j) {
      const int gn = n0 + wn * 64 + j * 16 + l16;
      const int hh = gn >> 6, dd = gn & (HD - 1);
      const float bv = bias[gn];
      if (z == 2) {
        union { u16 u[4]; uint2 v; } pk;
#pragma unroll
        for (int r = 0; r < 4; ++r) pk.u[r] = f2bf(acc[i][j][r] + bv);
        *reinterpret_cast<uint2*>(
            oz + ((size_t)(bb * NH + hh) * HD + dd) * SEQ + ss) = pk.v;
      } else {
        u16* op = oz + ((size_t)(bb * NH + hh) * SEQ + ss) * HD + dd;
#pragma unroll
        for (int r = 0; r < 4; ++r)
          op[(size_t)r * HD] = f2bf((acc[i][j][r] + bv) * qscale);
      }
    }
  }
}

// ---------------------------------------------------------------- out proj
__global__ __launch_bounds__(256) void gemm_out_kernel(
    const u16* __restrict__ A, const u16* __restrict__ W,
    const float* __restrict__ bias, float* __restrict__ Out) {
  __shared__ __align__(16) u16 As[128 * 32];
  __shared__ __align__(16) u16 Bs[128 * 32];

  const int tid = threadIdx.x;
  const int w = tid >> 6, lane = tid & 63;
  const int l16 = lane & 15, lg = lane >> 4;
  const int wm = w >> 1, wn = w & 1;

  const int m0 = blockIdx.x * 128;
  const int n0 = blockIdx.y * 128;

  f32x4 acc[4][4];
#pragma unroll
  for (int i = 0; i < 4; ++i)
#pragma unroll
    for (int j = 0; j < 4; ++j) {
      acc[i][j][0] = 0.f; acc[i][j][1] = 0.f;
      acc[i][j][2] = 0.f; acc[i][j][3] = 0.f;
    }

  for (int k0 = 0; k0 < DM; k0 += 32) {
#pragma unroll
    for (int i = 0; i < 2; ++i) {
      const int c = (w * 2 + i) * 64 + lane;
      const int m = c >> 2, kc = c & 3;
      GLDS16(A + (size_t)(m0 + m) * DM + (k0 + kc * 8),
             As + (size_t)(w * 2 + i) * 512);
      GLDS16(W + (size_t)(n0 + m) * DM + (k0 + kc * 8),
             Bs + (size_t)(w * 2 + i) * 512);
    }
    __syncthreads();
    bf16x8 af[4], bfv[4];
#pragma unroll
    for (int i = 0; i < 4; ++i)
      af[i] = ldb8(As + (wm * 64 + i * 16 + l16) * 32 + lg * 8);
#pragma unroll
    for (int j = 0; j < 4; ++j)
      bfv[j] = ldb8(Bs + (wn * 64 + j * 16 + l16) * 32 + lg * 8);
#pragma unroll
    for (int i = 0; i < 4; ++i)
#pragma unroll
      for (int j = 0; j < 4; ++j)
        acc[i][j] = mfma16(af[i], bfv[j], acc[i][j]);
    __syncthreads();
  }

#pragma unroll
  for (int i = 0; i < 4; ++i) {
    const int gm = m0 + wm * 64 + i * 16 + lg * 4;
#pragma unroll
    for (int j = 0; j < 4; ++j) {
      const int gn = n0 + wn * 64 + j * 16 + l16;
      const float bv = bias[gn];
      float* op = Out + (size_t)gm * DM + gn;
#pragma unroll
      for (int r = 0; r < 4; ++r)
        op[(size_t)r * DM] = acc[i][j][r] + bv;
    }
  }
}

// ---------------------------------------------------------------- attention
// 1-D grid of 768 blocks, longest-first: qt = 31 - idx/24, bh = idx%24.
// 4 waves x 32 q-rows, KV tile 64, double-buffered K/V LDS, 1 barrier/tile.
// Swapped QK^T (32x32x16): lane holds S^T[kv=crow(reg,hi)][q=lane&31].
__global__ __launch_bounds__(256) void attn_kernel(
    const u16* __restrict__ Qg, const u16* __restrict__ Kg,
    const u16* __restrict__ VTg, u16* __restrict__ Og) {
  __shared__ __align__(16) u16 Kt[2][64][72];   // [buf][kv][d], +8 pad
  __shared__ __align__(16) u16 Vt[2][64][72];   // [buf][d][kv], +8 pad (V^T)

  const int tid = threadIdx.x;
  const int w = tid >> 6, lane = tid & 63;
  const int l32 = lane & 31, hi = lane >> 5;

  const int idx = blockIdx.x;            // 0..767
  const int qt = 31 - (idx / 24);        // longest blocks dispatch first
  const int bh = idx % 24;
  const int bb = bh / NH, hh = bh % NH;

  const u16* Qp = Qg + (size_t)bh * SEQ * HD;
  const u16* Kp = Kg + (size_t)bh * SEQ * HD;
  const u16* VTp = VTg + (size_t)bh * HD * SEQ;

  const int qw0 = qt * 128 + w * 32;
  const int qlane = qw0 + l32;

  // Q fragments (B-operand): qf[c][j] = Q[q][c*16 + hi*8 + j]  (pre-scaled)
  bf16x8 qf[4];
#pragma unroll
  for (int c = 0; c < 4; ++c)
    qf[c] = ldb8(Qp + (size_t)qlane * HD + c * 16 + hi * 8);

  f32x16 oacc[2];  // O^T[32*db + crow(reg,hi)][q=l32]
#pragma unroll
  for (int db = 0; db < 2; ++db)
#pragma unroll
    for (int r = 0; r < 16; ++r) oacc[db][r] = 0.f;
  float mrun = -__builtin_inff();
  float lsum = 0.f;

  // staging coords: 8 threads per 64-elem row, rows srow and srow+32
  const int srow = tid >> 3;        // 0..31
  const int sc8 = (tid & 7) * 8;

  // ---- prologue: stage tile 0 into buffer 0
  {
    uint4 a = *reinterpret_cast<const uint4*>(Kp + (size_t)srow * HD + sc8);
    uint4 b = *reinterpret_cast<const uint4*>(
        Kp + (size_t)(srow + 32) * HD + sc8);
    uint4 c = *reinterpret_cast<const uint4*>(
        VTp + (size_t)srow * SEQ + sc8);
    uint4 d = *reinterpret_cast<const uint4*>(
        VTp + (size_t)(srow + 32) * SEQ + sc8);
    *reinterpret_cast<uint4*>(&Kt[0][srow][sc8]) = a;
    *reinterpret_cast<uint4*>(&Kt[0][srow + 32][sc8]) = b;
    *reinterpret_cast<uint4*>(&Vt[0][srow][sc8]) = c;
    *reinterpret_cast<uint4*>(&Vt[0][srow + 32][sc8]) = d;
  }

  const int NT = 2 * qt + 2;
  int cur = 0;
  for (int t = 0; t < NT; ++t) {
    const int kv0 = t * 64;
    const bool pf = (t + 1 < NT);
    uint4 nK0, nK1, nV0, nV1;
    if (pf) {  // prefetch next tile to regs (latency spans barrier + QK)
      const int nk = kv0 + 64;
      nK0 = *reinterpret_cast<const uint4*>(
          Kp + (size_t)(nk + srow) * HD + sc8);
      nK1 = *reinterpret_cast<const uint4*>(
          Kp + (size_t)(nk + srow + 32) * HD + sc8);
      nV0 = *reinterpret_cast<const uint4*>(
          VTp + (size_t)srow * SEQ + nk + sc8);
      nV1 = *reinterpret_cast<const uint4*>(
          VTp + (size_t)(srow + 32) * SEQ + nk + sc8);
    }
    __syncthreads();  // buf[cur] writes visible; prev reads of buf[cur^1] done

    const bool active = (kv0 <= qw0 + 31);
    f32x16 st[2];
    if (active) {
      // ---- QK^T (swapped): st[b] = S^T[kv=32b+crow][q]
      __builtin_amdgcn_s_setprio(1);
#pragma unroll
      for (int b = 0; b < 2; ++b) {
#pragma unroll
        for (int r = 0; r < 16; ++r) st[b][r] = 0.f;
#pragma unroll
        for (int c = 0; c < 4; ++c) {
          bf16x8 kf = ldb8(&Kt[cur][b * 32 + l32][c * 16 + hi * 8]);
          st[b] = mfma32(kf, qf[c], st[b]);
        }
      }
      __builtin_amdgcn_s_setprio(0);

      // ---- causal mask (diagonal tiles only)
      if (kv0 + 63 > qw0) {
#pragma unroll
        for (int b = 0; b < 2; ++b)
#pragma unroll
          for (int r = 0; r < 16; ++r) {
            const int kvi = kv0 + b * 32 + (r & 3) + 8 * (r >> 2) + 4 * hi;
            if (kvi > qlane) st[b][r] = -__builtin_inff();
          }
      }

      // ---- row max: 5-deep tree + partner combine
      float mx[8];
#pragma unroll
      for (int r = 0; r < 8; ++r)
        mx[r] = fmaxf(fmaxf(st[0][r], st[0][r + 8]),
                      fmaxf(st[1][r], st[1][r + 8]));
#pragma unroll
      for (int r = 0; r < 4; ++r) mx[r] = fmaxf(mx[r], mx[r + 4]);
      mx[0] = fmaxf(mx[0], mx[2]);
      mx[1] = fmaxf(mx[1], mx[3]);
      float mt = fmaxf(mx[0], mx[1]);
      mt = fmaxf(mt, __shfl_xor(mt, 32));

      // ---- defer-max (T13): only rescale when max grew materially
      if (__any(mt > mrun + 8.f)) {
        const float mnew = fmaxf(mrun, mt);
        const float corr = exp2f(mrun - mnew);  // 0 on first tile
        lsum *= corr;
#pragma unroll
        for (int db = 0; db < 2; ++db)
#pragma unroll
          for (int r = 0; r < 16; ++r) oacc[db][r] *= corr;
        mrun = mnew;
      }

      // ---- exp (log2 units) + tree row-sum
#pragma unroll
      for (int r = 0; r < 16; ++r) {
        st[0][r] = exp2f(st[0][r] - mrun);
        st[1][r] = exp2f(st[1][r] - mrun);
      }
      float sm[8];
#pragma unroll
      for (int r = 0; r < 8; ++r)
        sm[r] = (st[0][r] + st[0][r + 8]) + (st[1][r] + st[1][r + 8]);
#pragma unroll
      for (int r = 0; r < 4; ++r) sm[r] += sm[r + 4];
      lsum += (sm[0] + sm[2]) + (sm[1] + sm[3]);
    }

    if (pf) {  // write next tile into the other buffer (latency under PV)
      *reinterpret_cast<uint4*>(&Kt[cur ^ 1][srow][sc8]) = nK0;
      *reinterpret_cast<uint4*>(&Kt[cur ^ 1][srow + 32][sc8]) = nK1;
      *reinterpret_cast<uint4*>(&Vt[cur ^ 1][srow][sc8]) = nV0;
      *reinterpret_cast<uint4*>(&Vt[cur ^ 1][srow + 32][sc8]) = nV1;
    }

    if (active) {
      // ---- pack P to bf16 fragments (shfl partner exchange) and PV
#pragma unroll
      for (int b = 0; b < 2; ++b) {
#pragma unroll
        for (int h = 0; h < 2; ++h) {  // kv 16-chunk c = 2b + h
          u32 a0 = cvtpk(st[b][h * 8 + 0], st[b][h * 8 + 1]);
          u32 a1 = cvtpk(st[b][h * 8 + 2], st[b][h * 8 + 3]);
          u32 a2 = cvtpk(st[b][h * 8 + 4], st[b][h * 8 + 5]);
          u32 a3 = cvtpk(st[b][h * 8 + 6], st[b][h * 8 + 7]);
          const u32 p0 = (u32)__shfl_xor((int)a0, 32);
          const u32 p1 = (u32)__shfl_xor((int)a1, 32);
          const u32 p2 = (u32)__shfl_xor((int)a2, 32);
          const u32 p3 = (u32)__shfl_xor((int)a3, 32);
          union { u32 w[4]; bf16x8 v; } pb;
          pb.w[0] = hi ? p2 : a0;
          pb.w[1] = hi ? p3 : a1;
          pb.w[2] = hi ? a2 : p0;
          pb.w[3] = hi ? a3 : p1;
          const int c = 2 * b + h;
          __builtin_amdgcn_s_setprio(1);
#pragma unroll
          for (int db = 0; db < 2; ++db) {
            bf16x8 vf = ldb8(&Vt[cur][db * 32 + l32][c * 16 + hi * 8]);
            oacc[db] = mfma32(vf, pb.v, oacc[db]);
          }
          __builtin_amdgcn_s_setprio(0);
        }
      }
    }
    cur ^= 1;
  }

  // ---- combine partner halves of l, normalize, store O[q][d] bf16
  const float ltot = lsum + __shfl_xor(lsum, 32);
  const float linv = 1.f / ltot;

  u16* Op = Og + ((size_t)bb * SEQ + qlane) * DM + hh * HD;
#pragma unroll
  for (int db = 0; db < 2; ++db)
#pragma unroll
    for (int r = 0; r < 16; r += 2) {
      const int d = db * 32 + (r & 3) + 8 * (r >> 2) + 4 * hi;
      u32 pk = cvtpk(oacc[db][r] * linv, oacc[db][r + 1] * linv);
      *reinterpret_cast<u32*>(Op + d) = pk;
    }
}

// ---------------------------------------------------------------- launcher
extern "C" void kernel_launch(void* const* d_in, const int* in_sizes, int n_in,
                              void* d_out, int out_size, void* d_ws,
                              size_t ws_size, hipStream_t stream) {
  const float* x  = (const float*)d_in[0];
  const float* Wq = (const float*)d_in[1];
  const float* bq = (const float*)d_in[2];
  const float* Wk = (const float*)d_in[3];
  const float* bk = (const float*)d_in[4];
  const float* Wv = (const float*)d_in[5];
  const float* bv = (const float*)d_in[6];
  const float* Wo = (const float*)d_in[7];
  const float* bo = (const float*)d_in[8];
  float* out = (float*)d_out;

  u16* xb   = (u16*)d_ws;                       // [8192][768] bf16
  u16* Wall = xb + (size_t)MR * DM;             // 4 x [768][768] bf16
  u16* QKV  = Wall + (size_t)4 * DM * DM;       // Q,K: [bh][s][64]; V: [bh][d][s]
  u16* PRE  = QKV + (size_t)3 * MR * DM;        // [8192][768] bf16

  cvt_kernel<<<dim3(MR * DM / 8 / 256), 256, 0, stream>>>(x, xb, MR * DM / 8);
  cvt_w_kernel<<<dim3(DM * DM / 8 / 256, 4), 256, 0, stream>>>(Wq, Wk, Wv, Wo,
                                                               Wall);
  gemm_qkv_kernel<<<dim3(MR / 128, DM / 128, 3), 256, 0, stream>>>(
      xb, Wall, bq, bk, bv, QKV);
  attn_kernel<<<dim3(768), 256, 0, stream>>>(
      QKV, QKV + (size_t)MR * DM, QKV + (size_t)2 * MR * DM, PRE);
  gemm_out_kernel<<<dim3(MR / 128, DM / 128), 256, 0, stream>>>(
      PRE, Wall + (size_t)3 * DM * DM, bo, out);
}